// Round 1
// baseline (93.431 us; speedup 1.0000x reference)
//
#include <hip/hip_runtime.h>
#include <math.h>

// Problem constants (from reference): B=64, L=65536, widths {10,20,30,40},
// combined filter support d in [-40, 39] => 80 taps.
#define BLOCK 256
#define OPT 8                    // outputs per thread
#define TILE (BLOCK * OPT)       // 2048 outputs per block
#define HALO 48                  // aligned left halo (>= 40, multiple of 4)
#define NF 80                    // filter taps
#define LDSX (TILE + 2 * HALO)   // 2144 floats staged (covers [-48, +2095])

__global__ __launch_bounds__(BLOCK) void hann_fir_kernel(
    const float* __restrict__ x, const float* __restrict__ tw,
    float* __restrict__ out, int Ln)
{
    __shared__ float xs[LDSX];
    __shared__ float Fs[NF];

    const int tid = threadIdx.x;
    const int tiles_per_row = Ln / TILE;
    const int row = blockIdx.x / tiles_per_row;
    const int tile = blockIdx.x - row * tiles_per_row;
    const long long row_base = (long long)row * Ln;
    const int tile_start = tile * TILE;

    // ---- combined filter F into LDS (threads 0..79) ----
    if (tid < NF) {
        float t0 = tw[0], t1 = tw[1], t2 = tw[2], t3 = tw[3];
        float m = fmaxf(fmaxf(t0, t1), fmaxf(t2, t3));
        float e0 = expf(t0 - m), e1 = expf(t1 - m);
        float e2 = expf(t2 - m), e3 = expf(t3 - m);
        float inv = 1.0f / (e0 + e1 + e2 + e3);
        float wts[4] = {e0 * inv, e1 * inv, e2 * inv, e3 * inv};
        float f = 0.0f;
        #pragma unroll
        for (int t = 0; t < 4; ++t) {
            int w = 10 * (t + 1);
            int k = tid - 40 + w;            // hann index for this template
            if (k >= 0 && k < 2 * w) {
                float h = 0.5f - 0.5f * cosf(6.28318530717958647692f *
                                             (float)k / (float)(2 * w - 1));
                f += wts[t] * h;
            }
        }
        Fs[tid] = f;
    }

    // ---- stage x tile + halo into LDS, zero-padded at row edges ----
    // lds index i holds x[row, tile_start - HALO + i]
    #pragma unroll
    for (int i4 = tid; i4 < LDSX / 4; i4 += BLOCK) {
        int j = tile_start - HALO + 4 * i4;   // global col of element 0
        float4 v;
        if (j >= 0 && j + 3 < Ln) {
            v = *reinterpret_cast<const float4*>(x + row_base + j);
        } else {
            v.x = (j + 0 >= 0 && j + 0 < Ln) ? x[row_base + j + 0] : 0.0f;
            v.y = (j + 1 >= 0 && j + 1 < Ln) ? x[row_base + j + 1] : 0.0f;
            v.z = (j + 2 >= 0 && j + 2 < Ln) ? x[row_base + j + 2] : 0.0f;
            v.w = (j + 3 >= 0 && j + 3 < Ln) ? x[row_base + j + 3] : 0.0f;
        }
        *reinterpret_cast<float4*>(xs + 4 * i4) = v;
    }
    __syncthreads();

    // ---- FIR: 8 consecutive outputs per thread, rolling 12-float window ----
    // output j0 = tile_start + 8*tid + r, r in [0,8)
    // needs x[j0 - 40 .. j0 + 39]; lds index of x[j] = j - tile_start + HALO
    float acc[OPT];
    #pragma unroll
    for (int r = 0; r < OPT; ++r) acc[r] = 0.0f;

    const float4* xs4 = reinterpret_cast<const float4*>(xs);
    const float4* Fs4 = reinterpret_cast<const float4*>(Fs);
    const int b4 = 2 * tid + (HALO - 40) / 4;   // float4 idx of x[j0 - 40]

    float4 c0 = xs4[b4];
    float4 c1 = xs4[b4 + 1];
    #pragma unroll
    for (int g = 0; g < NF / 4; ++g) {          // 20 groups of 4 taps
        float4 c2 = xs4[b4 + g + 2];
        float4 f = Fs4[g];
        float win[12] = {c0.x, c0.y, c0.z, c0.w,
                         c1.x, c1.y, c1.z, c1.w,
                         c2.x, c2.y, c2.z, c2.w};
        #pragma unroll
        for (int r = 0; r < OPT; ++r) {
            acc[r] = fmaf(f.x, win[r + 0], acc[r]);
            acc[r] = fmaf(f.y, win[r + 1], acc[r]);
            acc[r] = fmaf(f.z, win[r + 2], acc[r]);
            acc[r] = fmaf(f.w, win[r + 3], acc[r]);
        }
        c0 = c1; c1 = c2;
    }

    // ---- store 8 consecutive outputs as two aligned float4 ----
    const long long o = row_base + tile_start + OPT * tid;
    float4 o0 = {acc[0], acc[1], acc[2], acc[3]};
    float4 o1 = {acc[4], acc[5], acc[6], acc[7]};
    *reinterpret_cast<float4*>(out + o) = o0;
    *reinterpret_cast<float4*>(out + o + 4) = o1;
}

extern "C" void kernel_launch(void* const* d_in, const int* in_sizes, int n_in,
                              void* d_out, int out_size, void* d_ws, size_t ws_size,
                              hipStream_t stream) {
    const float* x  = (const float*)d_in[0];   // [B, L] fp32
    const float* tw = (const float*)d_in[1];   // [4] fp32
    float* out = (float*)d_out;                // [B, L] fp32

    const int B = 64;
    const int L = 65536;
    (void)in_sizes; (void)n_in; (void)out_size; (void)d_ws; (void)ws_size;

    const int tiles_per_row = L / TILE;        // 32
    dim3 grid(B * tiles_per_row);              // 2048 blocks
    dim3 block(BLOCK);
    hann_fir_kernel<<<grid, block, 0, stream>>>(x, tw, out, L);
}

// Round 3
// 75.065 us; speedup vs baseline: 1.2447x; 1.2447x over previous
//
#include <hip/hip_runtime.h>
#include <math.h>

// Problem constants: B=64, L=65536, widths {10,20,30,40},
// combined symmetric filter support d in [-40, 39] => 80 taps.
#define BLOCK 256
#define OPT 8                    // outputs per thread
#define TILE (BLOCK * OPT)       // 2048 outputs per block
#define HALO 48                  // aligned left halo (>= 40, multiple of 4)
#define NF 80                    // filter taps
#define LDSX4 (TILE / 4 + 2 * HALO / 4)   // 536 logical float4
// bank-conflict pad: 1 float4 inserted every 8 float4s
#define PHYS4(i) ((i) + ((i) >> 3))
#define LDSP4 (LDSX4 + LDSX4 / 8 + 2)     // 605 physical float4

typedef float nfloat4 __attribute__((ext_vector_type(4)));

__global__ __launch_bounds__(BLOCK) void hann_fir_kernel(
    const float* __restrict__ x, const float* __restrict__ tw,
    float* __restrict__ out, int Ln)
{
    __shared__ float4 xs4[LDSP4];
    __shared__ float Fs[NF];

    const int tid = threadIdx.x;
    const int tiles_per_row = Ln / TILE;
    const int row = blockIdx.x / tiles_per_row;
    const int tile = blockIdx.x - row * tiles_per_row;
    const long long row_base = (long long)row * Ln;
    const int tile_start = tile * TILE;

    // ---- combined filter F into LDS (threads 0..79) ----
    if (tid < NF) {
        float t0 = tw[0], t1 = tw[1], t2 = tw[2], t3 = tw[3];
        float m = fmaxf(fmaxf(t0, t1), fmaxf(t2, t3));
        float e0 = expf(t0 - m), e1 = expf(t1 - m);
        float e2 = expf(t2 - m), e3 = expf(t3 - m);
        float inv = 1.0f / (e0 + e1 + e2 + e3);
        float wts[4] = {e0 * inv, e1 * inv, e2 * inv, e3 * inv};
        float f = 0.0f;
        #pragma unroll
        for (int t = 0; t < 4; ++t) {
            int w = 10 * (t + 1);
            int k = tid - 40 + w;            // hann index for this template
            if (k >= 0 && k < 2 * w) {
                float h = 0.5f - 0.5f * cosf(6.28318530717958647692f *
                                             (float)k / (float)(2 * w - 1));
                f += wts[t] * h;
            }
        }
        Fs[tid] = f;
    }

    // ---- stage x tile + halo into LDS (padded layout), zero at row edges ----
    // logical float4 i4 holds x[row, tile_start - HALO + 4*i4 .. +3]
    for (int i4 = tid; i4 < LDSX4; i4 += BLOCK) {
        int j = tile_start - HALO + 4 * i4;   // global col of element 0
        float4 v;
        if (j >= 0 && j + 3 < Ln) {
            v = *reinterpret_cast<const float4*>(x + row_base + j);
        } else {
            v.x = (j + 0 >= 0 && j + 0 < Ln) ? x[row_base + j + 0] : 0.0f;
            v.y = (j + 1 >= 0 && j + 1 < Ln) ? x[row_base + j + 1] : 0.0f;
            v.z = (j + 2 >= 0 && j + 2 < Ln) ? x[row_base + j + 2] : 0.0f;
            v.w = (j + 3 >= 0 && j + 3 < Ln) ? x[row_base + j + 3] : 0.0f;
        }
        xs4[PHYS4(i4)] = v;
    }
    __syncthreads();

    // ---- FIR: 8 consecutive outputs per thread, rolling 12-float window ----
    // output j0 = tile_start + 8*tid + r, r in [0,8)
    float acc[OPT];
    #pragma unroll
    for (int r = 0; r < OPT; ++r) acc[r] = 0.0f;

    const float4* Fs4 = reinterpret_cast<const float4*>(Fs);
    const int b4 = 2 * tid + (HALO - 40) / 4;   // logical float4 idx of x[j0-40]

    float4 c0 = xs4[PHYS4(b4)];
    float4 c1 = xs4[PHYS4(b4 + 1)];
    #pragma unroll
    for (int g = 0; g < NF / 4; ++g) {          // 20 groups of 4 taps
        float4 c2 = xs4[PHYS4(b4 + g + 2)];
        float4 f = Fs4[g];
        float win[12] = {c0.x, c0.y, c0.z, c0.w,
                         c1.x, c1.y, c1.z, c1.w,
                         c2.x, c2.y, c2.z, c2.w};
        #pragma unroll
        for (int r = 0; r < OPT; ++r) {
            acc[r] = fmaf(f.x, win[r + 0], acc[r]);
            acc[r] = fmaf(f.y, win[r + 1], acc[r]);
            acc[r] = fmaf(f.z, win[r + 2], acc[r]);
            acc[r] = fmaf(f.w, win[r + 3], acc[r]);
        }
        c0 = c1; c1 = c2;
    }

    // ---- store 8 consecutive outputs as two aligned 16B nontemporal stores ----
    const long long o = row_base + tile_start + OPT * tid;
    nfloat4 o0 = {acc[0], acc[1], acc[2], acc[3]};
    nfloat4 o1 = {acc[4], acc[5], acc[6], acc[7]};
    __builtin_nontemporal_store(o0, reinterpret_cast<nfloat4*>(out + o));
    __builtin_nontemporal_store(o1, reinterpret_cast<nfloat4*>(out + o + 4));
}

extern "C" void kernel_launch(void* const* d_in, const int* in_sizes, int n_in,
                              void* d_out, int out_size, void* d_ws, size_t ws_size,
                              hipStream_t stream) {
    const float* x  = (const float*)d_in[0];   // [B, L] fp32
    const float* tw = (const float*)d_in[1];   // [4] fp32
    float* out = (float*)d_out;                // [B, L] fp32

    const int B = 64;
    const int L = 65536;
    (void)in_sizes; (void)n_in; (void)out_size; (void)d_ws; (void)ws_size;

    const int tiles_per_row = L / TILE;        // 32
    dim3 grid(B * tiles_per_row);              // 2048 blocks
    dim3 block(BLOCK);
    hann_fir_kernel<<<grid, block, 0, stream>>>(x, tw, out, L);
}